// Round 1
// baseline (1028.802 us; speedup 1.0000x reference)
//
#include <hip/hip_runtime.h>

#define BB   256
#define SS   64
#define DD   512
#define HH   8
#define DKK  64
#define BSZ  16384   // B*S
#define INSZ 32768
#define DFF  2048
#define NOUT 50
#define KSF  128     // final gemm split-K count
#define KCF  256     // 32768 / KSF

typedef float f32x4 __attribute__((ext_vector_type(4)));
typedef __bf16 bf16x8 __attribute__((ext_vector_type(8)));
typedef unsigned short u16x8 __attribute__((ext_vector_type(8)));

__device__ inline unsigned short f2bf(float f) {
    unsigned u = __builtin_bit_cast(unsigned, f);
    u += 0x7FFFu + ((u >> 16) & 1u);   // RNE
    return (unsigned short)(u >> 16);
}
__device__ inline bf16x8 ld_frag(const unsigned short* p) {
    return __builtin_bit_cast(bf16x8, *(const u16x8*)p);
}
#define MFMA(a,b,c) __builtin_amdgcn_mfma_f32_16x16x32_bf16(a,b,c,0,0,0)

// ---------------------------------------------------------------- QKV
// grid (256 m-tiles, 8 heads), block 256. Computes q,k,v[b][h][s][dk] bf16,
// q pre-scaled by 1/sqrt(DK).
__global__ __launch_bounds__(256) void k_qkv(
    const float* __restrict__ X,  const float* __restrict__ Wq,
    const float* __restrict__ bq, const float* __restrict__ Wk,
    const float* __restrict__ bk, const float* __restrict__ Wv,
    const float* __restrict__ bv, unsigned short* __restrict__ qkv)
{
    const int mt = blockIdx.x, h = blockIdx.y;
    const int tid = threadIdx.x, wave = tid >> 6, lane = tid & 63;
    const int m0 = mt * 64;
    __shared__ unsigned short Xs[64][72];
    __shared__ unsigned short Ws[192][72];   // [w3*64 + n][k]

    const float* Wb0 = Wq + (size_t)h * DD * DKK;
    const float* Wb1 = Wk + (size_t)h * DD * DKK;
    const float* Wb2 = Wv + (size_t)h * DD * DKK;

    f32x4 acc[12] = {};
    for (int k0 = 0; k0 < DD; k0 += 64) {
        for (int p = 0; p < 4; ++p) {                     // X chunk 64x64
            int e = tid + p * 256;
            int r = e >> 4, c4 = e & 15;
            float4 v = *(const float4*)(X + (size_t)(m0 + r) * DD + k0 + c4 * 4);
            int c = c4 * 4;
            Xs[r][c] = f2bf(v.x); Xs[r][c+1] = f2bf(v.y);
            Xs[r][c+2] = f2bf(v.z); Xs[r][c+3] = f2bf(v.w);
        }
        for (int w3 = 0; w3 < 3; ++w3) {                  // W chunks transposed
            const float* W = (w3 == 0) ? Wb0 : (w3 == 1) ? Wb1 : Wb2;
            for (int p = 0; p < 4; ++p) {
                int e = tid + p * 256;                    // 1024 float4
                int kr = e >> 4, c4 = e & 15;
                float4 v = *(const float4*)(W + (size_t)(k0 + kr) * DKK + c4 * 4);
                int nb = w3 * 64 + c4 * 4;
                Ws[nb][kr] = f2bf(v.x); Ws[nb+1][kr] = f2bf(v.y);
                Ws[nb+2][kr] = f2bf(v.z); Ws[nb+3][kr] = f2bf(v.w);
            }
        }
        __syncthreads();
        for (int ks = 0; ks < 64; ks += 32) {
            bf16x8 a = ld_frag(&Xs[wave*16 + (lane & 15)][ks + (lane >> 4) * 8]);
            for (int nt = 0; nt < 12; ++nt) {
                bf16x8 b = ld_frag(&Ws[nt*16 + (lane & 15)][ks + (lane >> 4) * 8]);
                acc[nt] = MFMA(a, b, acc[nt]);
            }
        }
        __syncthreads();
    }
    for (int nt = 0; nt < 12; ++nt) {
        int w3 = nt >> 2;
        const float* bias = ((w3 == 0) ? bq : (w3 == 1) ? bk : bv) + h * DKK;
        float scale = (w3 == 0) ? 0.125f : 1.0f;
        unsigned short* out = qkv + ((size_t)(w3 * BB + mt) * HH + h) * (SS * DKK);
        for (int r = 0; r < 4; ++r) {
            int s = wave * 16 + (lane >> 4) * 4 + r;
            int c = (nt & 3) * 16 + (lane & 15);
            out[s * DKK + c] = f2bf((acc[nt][r] + bias[c]) * scale);
        }
    }
}

// ---------------------------------------------------------------- attention
// grid 2048 (b*8+h), block 256. ctx[b][s][h*64+dv] bf16.
__global__ __launch_bounds__(256) void k_attn(
    const unsigned short* __restrict__ qkv, unsigned short* __restrict__ ctx)
{
    const int b = blockIdx.x >> 3, h = blockIdx.x & 7;
    const int tid = threadIdx.x, wave = tid >> 6, lane = tid & 63;
    __shared__ unsigned short Qs[64][72], Ks[64][72], Vt[64][72], Ps[64][72];

    const unsigned short* qp = qkv + ((size_t)(0 * BB + b) * HH + h) * 4096;
    const unsigned short* kp = qkv + ((size_t)(1 * BB + b) * HH + h) * 4096;
    const unsigned short* vp = qkv + ((size_t)(2 * BB + b) * HH + h) * 4096;

    for (int p = 0; p < 4; ++p) {
        int e = tid + p * 256;
        int r = e >> 4, c4 = (e & 15) * 4;
        *(ushort4*)&Qs[r][c4] = *(const ushort4*)(qp + r * 64 + c4);
        *(ushort4*)&Ks[r][c4] = *(const ushort4*)(kp + r * 64 + c4);
    }
    for (int p = 0; p < 16; ++p) {                        // V transposed
        int e = tid + p * 256;
        int t = e >> 6, dv = e & 63;
        Vt[dv][t] = vp[t * 64 + dv];
    }
    __syncthreads();

    f32x4 sa[4] = {};
    for (int ks = 0; ks < 64; ks += 32) {
        bf16x8 a = ld_frag(&Qs[wave*16 + (lane & 15)][ks + (lane >> 4) * 8]);
        for (int nt = 0; nt < 4; ++nt) {
            bf16x8 bb = ld_frag(&Ks[nt*16 + (lane & 15)][ks + (lane >> 4) * 8]);
            sa[nt] = MFMA(a, bb, sa[nt]);
        }
    }
    for (int r = 0; r < 4; ++r) {                         // softmax over cols
        float mx = fmaxf(fmaxf(sa[0][r], sa[1][r]), fmaxf(sa[2][r], sa[3][r]));
        for (int off = 1; off < 16; off <<= 1) mx = fmaxf(mx, __shfl_xor(mx, off, 64));
        float e0 = __expf(sa[0][r] - mx), e1 = __expf(sa[1][r] - mx);
        float e2 = __expf(sa[2][r] - mx), e3 = __expf(sa[3][r] - mx);
        float sm = e0 + e1 + e2 + e3;
        for (int off = 1; off < 16; off <<= 1) sm += __shfl_xor(sm, off, 64);
        float inv = 1.f / sm;
        sa[0][r] = e0 * inv; sa[1][r] = e1 * inv; sa[2][r] = e2 * inv; sa[3][r] = e3 * inv;
    }
    for (int nt = 0; nt < 4; ++nt)
        for (int r = 0; r < 4; ++r)
            Ps[wave*16 + (lane >> 4) * 4 + r][nt*16 + (lane & 15)] = f2bf(sa[nt][r]);
    __syncthreads();

    f32x4 oa[4] = {};
    for (int ks = 0; ks < 64; ks += 32) {
        bf16x8 a = ld_frag(&Ps[wave*16 + (lane & 15)][ks + (lane >> 4) * 8]);
        for (int nt = 0; nt < 4; ++nt) {
            bf16x8 bb = ld_frag(&Vt[nt*16 + (lane & 15)][ks + (lane >> 4) * 8]);
            oa[nt] = MFMA(a, bb, oa[nt]);
        }
    }
    unsigned short* cp = ctx + (size_t)b * SS * DD + h * DKK;
    for (int nt = 0; nt < 4; ++nt)
        for (int r = 0; r < 4; ++r) {
            int s = wave * 16 + (lane >> 4) * 4 + r;
            int dv = nt * 16 + (lane & 15);
            cp[(size_t)s * DD + dv] = f2bf(oa[nt][r]);
        }
}

// ---------------------------------------------------------------- out-proj
// grid (256, 4): tile M=64, N=128, K=512. t1 = ctx@Wo + bo + X
__global__ __launch_bounds__(256) void k_oproj(
    const unsigned short* __restrict__ ctx, const float* __restrict__ Wo,
    const float* __restrict__ bo, const float* __restrict__ X,
    float* __restrict__ t1)
{
    const int mt = blockIdx.x, n0 = blockIdx.y * 128;
    const int tid = threadIdx.x, wave = tid >> 6, lane = tid & 63;
    const int m0 = mt * 64;
    __shared__ unsigned short As[64][72], Bs[128][72];
    f32x4 acc[8] = {};
    for (int k0 = 0; k0 < DD; k0 += 64) {
        for (int p = 0; p < 4; ++p) {
            int e = tid + p * 256; int r = e >> 4, c4 = (e & 15) * 4;
            *(ushort4*)&As[r][c4] = *(const ushort4*)(ctx + (size_t)(m0 + r) * DD + k0 + c4);
        }
        for (int p = 0; p < 8; ++p) {
            int e = tid + p * 256; int kr = e >> 5, c4 = e & 31;
            float4 v = *(const float4*)(Wo + (size_t)(k0 + kr) * DD + n0 + c4 * 4);
            int nb = c4 * 4;
            Bs[nb][kr] = f2bf(v.x); Bs[nb+1][kr] = f2bf(v.y);
            Bs[nb+2][kr] = f2bf(v.z); Bs[nb+3][kr] = f2bf(v.w);
        }
        __syncthreads();
        for (int ks = 0; ks < 64; ks += 32) {
            bf16x8 a = ld_frag(&As[wave*16 + (lane & 15)][ks + (lane >> 4) * 8]);
            for (int nt = 0; nt < 8; ++nt) {
                bf16x8 bb = ld_frag(&Bs[nt*16 + (lane & 15)][ks + (lane >> 4) * 8]);
                acc[nt] = MFMA(a, bb, acc[nt]);
            }
        }
        __syncthreads();
    }
    for (int nt = 0; nt < 8; ++nt)
        for (int r = 0; r < 4; ++r) {
            int m = m0 + wave * 16 + (lane >> 4) * 4 + r;
            int n = n0 + nt * 16 + (lane & 15);
            t1[(size_t)m * DD + n] = acc[nt][r] + bo[n] + X[(size_t)m * DD + n];
        }
}

// ---------------------------------------------------------------- LN1 (in place) + bf16 copy
__global__ __launch_bounds__(256) void k_ln1(
    float* __restrict__ t1, const float* __restrict__ g,
    const float* __restrict__ bv, unsigned short* __restrict__ hs16)
{
    const int tid = threadIdx.x, wave = tid >> 6, lane = tid & 63;
    const int row = blockIdx.x * 4 + wave;
    float* p = t1 + (size_t)row * DD;
    float4 v0 = *(const float4*)(p + lane * 4);
    float4 v1 = *(const float4*)(p + 256 + lane * 4);
    float s = v0.x + v0.y + v0.z + v0.w + v1.x + v1.y + v1.z + v1.w;
    float q = v0.x*v0.x + v0.y*v0.y + v0.z*v0.z + v0.w*v0.w
            + v1.x*v1.x + v1.y*v1.y + v1.z*v1.z + v1.w*v1.w;
    for (int off = 1; off < 64; off <<= 1) { s += __shfl_xor(s, off, 64); q += __shfl_xor(q, off, 64); }
    float mu = s / DD;
    float rs = rsqrtf(q / DD - mu * mu + 1e-5f);
    float4 g0 = *(const float4*)(g + lane * 4), g1 = *(const float4*)(g + 256 + lane * 4);
    float4 b0 = *(const float4*)(bv + lane * 4), b1 = *(const float4*)(bv + 256 + lane * 4);
    float4 o0, o1;
    o0.x = (v0.x - mu) * rs * g0.x + b0.x; o0.y = (v0.y - mu) * rs * g0.y + b0.y;
    o0.z = (v0.z - mu) * rs * g0.z + b0.z; o0.w = (v0.w - mu) * rs * g0.w + b0.w;
    o1.x = (v1.x - mu) * rs * g1.x + b1.x; o1.y = (v1.y - mu) * rs * g1.y + b1.y;
    o1.z = (v1.z - mu) * rs * g1.z + b1.z; o1.w = (v1.w - mu) * rs * g1.w + b1.w;
    *(float4*)(p + lane * 4) = o0;
    *(float4*)(p + 256 + lane * 4) = o1;
    unsigned short* hp = hs16 + (size_t)row * DD;
    ushort4 u;
    u.x = f2bf(o0.x); u.y = f2bf(o0.y); u.z = f2bf(o0.z); u.w = f2bf(o0.w);
    *(ushort4*)(hp + lane * 4) = u;
    u.x = f2bf(o1.x); u.y = f2bf(o1.y); u.z = f2bf(o1.z); u.w = f2bf(o1.w);
    *(ushort4*)(hp + 256 + lane * 4) = u;
}

// ---------------------------------------------------------------- FFN1 split-K
// grid (32 n-tiles of 64, 16 k-splits of 2048), block 256. M=256 whole.
__global__ __launch_bounds__(256) void k_ffn1(
    const unsigned short* __restrict__ hs16, const float* __restrict__ W1,
    float* __restrict__ part)
{
    const int n0 = blockIdx.x * 64, kbase = blockIdx.y * 2048;
    const int tid = threadIdx.x, wave = tid >> 6, lane = tid & 63;
    __shared__ unsigned short As[256][72], Bs[64][72];
    f32x4 acc[4][4] = {};
    for (int kc = 0; kc < 2048; kc += 64) {
        int k0 = kbase + kc;
        for (int p = 0; p < 16; ++p) {
            int e = tid + p * 256; int r = e >> 4, c4 = (e & 15) * 4;
            *(ushort4*)&As[r][c4] = *(const ushort4*)(hs16 + (size_t)r * INSZ + k0 + c4);
        }
        for (int p = 0; p < 4; ++p) {
            int e = tid + p * 256; int kr = e >> 4, c4 = e & 15;
            float4 v = *(const float4*)(W1 + (size_t)(k0 + kr) * DFF + n0 + c4 * 4);
            int nb = c4 * 4;
            Bs[nb][kr] = f2bf(v.x); Bs[nb+1][kr] = f2bf(v.y);
            Bs[nb+2][kr] = f2bf(v.z); Bs[nb+3][kr] = f2bf(v.w);
        }
        __syncthreads();
        for (int ks = 0; ks < 64; ks += 32) {
            bf16x8 bfr[4];
            for (int nt = 0; nt < 4; ++nt)
                bfr[nt] = ld_frag(&Bs[nt*16 + (lane & 15)][ks + (lane >> 4) * 8]);
            for (int mt2 = 0; mt2 < 4; ++mt2) {
                bf16x8 a = ld_frag(&As[wave*64 + mt2*16 + (lane & 15)][ks + (lane >> 4) * 8]);
                for (int nt = 0; nt < 4; ++nt) acc[mt2][nt] = MFMA(a, bfr[nt], acc[mt2][nt]);
            }
        }
        __syncthreads();
    }
    float* pp = part + (size_t)blockIdx.y * 256 * DFF;
    for (int mt2 = 0; mt2 < 4; ++mt2)
        for (int nt = 0; nt < 4; ++nt)
            for (int r = 0; r < 4; ++r) {
                int m = wave * 64 + mt2 * 16 + (lane >> 4) * 4 + r;
                int n = n0 + nt * 16 + (lane & 15);
                pp[(size_t)m * DFF + n] = acc[mt2][nt][r];
            }
}

__global__ __launch_bounds__(256) void k_ffn1red(
    const float* __restrict__ part, const float* __restrict__ b1,
    unsigned short* __restrict__ h16)
{
    int e = blockIdx.x * 256 + threadIdx.x;   // float4 index
    int m = e >> 9;
    int c = (e & 511) * 4;
    float4 s = {0.f, 0.f, 0.f, 0.f};
    for (int p = 0; p < 16; ++p) {
        float4 v = *(const float4*)(part + ((size_t)p * 256 + m) * DFF + c);
        s.x += v.x; s.y += v.y; s.z += v.z; s.w += v.w;
    }
    float4 bb = *(const float4*)(b1 + c);
    s.x = fmaxf(s.x + bb.x, 0.f); s.y = fmaxf(s.y + bb.y, 0.f);
    s.z = fmaxf(s.z + bb.z, 0.f); s.w = fmaxf(s.w + bb.w, 0.f);
    ushort4 u; u.x = f2bf(s.x); u.y = f2bf(s.y); u.z = f2bf(s.z); u.w = f2bf(s.w);
    *(ushort4*)(h16 + (size_t)m * DFF + c) = u;
}

// ---------------------------------------------------------------- FFN2 + residual
// grid 512 n-tiles of 64, K=2048 full. t2 = h@W2 + b2 + hs32
__global__ __launch_bounds__(256) void k_ffn2(
    const unsigned short* __restrict__ h16, const float* __restrict__ W2,
    const float* __restrict__ b2, const float* __restrict__ hs32,
    float* __restrict__ t2)
{
    const int n0 = blockIdx.x * 64;
    const int tid = threadIdx.x, wave = tid >> 6, lane = tid & 63;
    __shared__ unsigned short As[256][72], Bs[64][72];
    f32x4 acc[4][4] = {};
    for (int k0 = 0; k0 < DFF; k0 += 64) {
        for (int p = 0; p < 16; ++p) {
            int e = tid + p * 256; int r = e >> 4, c4 = (e & 15) * 4;
            *(ushort4*)&As[r][c4] = *(const ushort4*)(h16 + (size_t)r * DFF + k0 + c4);
        }
        for (int p = 0; p < 4; ++p) {
            int e = tid + p * 256; int kr = e >> 4, c4 = e & 15;
            float4 v = *(const float4*)(W2 + (size_t)(k0 + kr) * INSZ + n0 + c4 * 4);
            int nb = c4 * 4;
            Bs[nb][kr] = f2bf(v.x); Bs[nb+1][kr] = f2bf(v.y);
            Bs[nb+2][kr] = f2bf(v.z); Bs[nb+3][kr] = f2bf(v.w);
        }
        __syncthreads();
        for (int ks = 0; ks < 64; ks += 32) {
            bf16x8 bfr[4];
            for (int nt = 0; nt < 4; ++nt)
                bfr[nt] = ld_frag(&Bs[nt*16 + (lane & 15)][ks + (lane >> 4) * 8]);
            for (int mt2 = 0; mt2 < 4; ++mt2) {
                bf16x8 a = ld_frag(&As[wave*64 + mt2*16 + (lane & 15)][ks + (lane >> 4) * 8]);
                for (int nt = 0; nt < 4; ++nt) acc[mt2][nt] = MFMA(a, bfr[nt], acc[mt2][nt]);
            }
        }
        __syncthreads();
    }
    for (int mt2 = 0; mt2 < 4; ++mt2)
        for (int nt = 0; nt < 4; ++nt)
            for (int r = 0; r < 4; ++r) {
                int m = wave * 64 + mt2 * 16 + (lane >> 4) * 4 + r;
                int n = n0 + nt * 16 + (lane & 15);
                size_t idx = (size_t)m * INSZ + n;
                t2[idx] = acc[mt2][nt][r] + b2[n] + hs32[idx];
            }
}

// ---------------------------------------------------------------- LN2 stats
__global__ __launch_bounds__(256) void k_ln2stats(
    const float* __restrict__ t2, float* __restrict__ stats)
{
    const int m = blockIdx.x, tid = threadIdx.x;
    const float* p = t2 + (size_t)m * INSZ;
    float s = 0.f, q = 0.f;
    for (int i = tid; i < INSZ / 4; i += 256) {
        float4 v = *(const float4*)(p + i * 4);
        s += v.x + v.y + v.z + v.w;
        q += v.x*v.x + v.y*v.y + v.z*v.z + v.w*v.w;
    }
    for (int off = 1; off < 64; off <<= 1) { s += __shfl_xor(s, off, 64); q += __shfl_xor(q, off, 64); }
    __shared__ float ss[4], qq[4];
    if ((tid & 63) == 0) { ss[tid >> 6] = s; qq[tid >> 6] = q; }
    __syncthreads();
    if (tid == 0) {
        s = ss[0] + ss[1] + ss[2] + ss[3];
        q = qq[0] + qq[1] + qq[2] + qq[3];
        float mu = s / INSZ;
        stats[m * 2] = mu;
        stats[m * 2 + 1] = rsqrtf(q / INSZ - mu * mu + 1e-5f);
    }
}

// ---------------------------------------------------------------- final GEMM (LN folded)
// A rows: 0..255 = t2*g ; 256 = g ; 257 = b ; 258..271 = 0. Split-K over 128 blocks.
__global__ __launch_bounds__(256) void k_fgemm(
    const float* __restrict__ t2, const float* __restrict__ g,
    const float* __restrict__ bv, const float* __restrict__ Wf,
    float* __restrict__ fpart)
{
    const int sp = blockIdx.x, kbase = sp * KCF;
    const int tid = threadIdx.x, wave = tid >> 6, lane = tid & 63;
    __shared__ unsigned short As[272][72], Bs[64][72];
    f32x4 acc[5][4] = {};
    for (int kc = 0; kc < KCF; kc += 64) {
        int k0 = kbase + kc;
        for (int p = 0; p < 68; ++p) {                    // 272x64 scalars
            int e = tid + p * 256;
            int r = e >> 6, c = e & 63;
            int k = k0 + c;
            float val;
            if (r < 256)      val = t2[(size_t)r * INSZ + k] * g[k];
            else if (r == 256) val = g[k];
            else if (r == 257) val = bv[k];
            else               val = 0.f;
            As[r][c] = f2bf(val);
        }
        for (int p = 0; p < 16; ++p) {                    // Wf chunk, n padded to 64
            int e = tid + p * 256;
            int kr = e >> 6, n = e & 63;
            Bs[n][kr] = (n < NOUT) ? f2bf(Wf[(size_t)(k0 + kr) * NOUT + n]) : (unsigned short)0;
        }
        __syncthreads();
        for (int ks = 0; ks < 64; ks += 32) {
            bf16x8 bfr[4];
            for (int nt = 0; nt < 4; ++nt)
                bfr[nt] = ld_frag(&Bs[nt*16 + (lane & 15)][ks + (lane >> 4) * 8]);
            int i = 0;
            for (int mt = wave; mt < 17; mt += 4, ++i) {
                bf16x8 a = ld_frag(&As[mt*16 + (lane & 15)][ks + (lane >> 4) * 8]);
                for (int nt = 0; nt < 4; ++nt) acc[i][nt] = MFMA(a, bfr[nt], acc[i][nt]);
            }
        }
        __syncthreads();
    }
    float* pp = fpart + (size_t)sp * 272 * 64;
    int i = 0;
    for (int mt = wave; mt < 17; mt += 4, ++i)
        for (int nt = 0; nt < 4; ++nt)
            for (int r = 0; r < 4; ++r) {
                int m = mt * 16 + (lane >> 4) * 4 + r;
                int n = nt * 16 + (lane & 15);
                pp[m * 64 + n] = acc[i][nt][r];
            }
}

__global__ __launch_bounds__(64) void k_fout(
    const float* __restrict__ fpart, const float* __restrict__ stats,
    const float* __restrict__ bf_, float* __restrict__ out)
{
    const int m = blockIdx.x, n = threadIdx.x;
    float s = 0.f, sg = 0.f, sb = 0.f;
    for (int sp = 0; sp < KSF; ++sp) {
        const float* pp = fpart + (size_t)sp * 272 * 64;
        s  += pp[m * 64 + n];
        sg += pp[256 * 64 + n];
        sb += pp[257 * 64 + n];
    }
    if (n < NOUT) {
        float mu = stats[m * 2], rs = stats[m * 2 + 1];
        out[m * NOUT + n] = rs * (s - mu * sg) + sb + bf_[n];
    }
}

// ---------------------------------------------------------------- launch
extern "C" void kernel_launch(void* const* d_in, const int* in_sizes, int n_in,
                              void* d_out, int out_size, void* d_ws, size_t ws_size,
                              hipStream_t stream) {
    const float* X   = (const float*)d_in[0];
    const float* Wq  = (const float*)d_in[1];
    const float* bq  = (const float*)d_in[2];
    const float* Wk  = (const float*)d_in[3];
    const float* bk  = (const float*)d_in[4];
    const float* Wv  = (const float*)d_in[5];
    const float* bv  = (const float*)d_in[6];
    const float* Wo  = (const float*)d_in[7];
    const float* bo  = (const float*)d_in[8];
    const float* g1  = (const float*)d_in[9];
    const float* b1v = (const float*)d_in[10];
    const float* W1  = (const float*)d_in[11];
    const float* b1  = (const float*)d_in[12];
    const float* W2  = (const float*)d_in[13];
    const float* b2  = (const float*)d_in[14];
    const float* g2  = (const float*)d_in[15];
    const float* b2v = (const float*)d_in[16];
    const float* Wf  = (const float*)d_in[17];
    const float* bfv = (const float*)d_in[18];
    float* out = (float*)d_out;
    char* ws = (char*)d_ws;

    // workspace overlay (liveness-checked):
    // [0, 50.33M)   : qkv bf16 (k1-k2) -> part1 (k5-k6) -> fpart (k9-k10)
    // [33.55M,50.33M): hs16 (k4-k5)  [disjoint from part1's [0,33.55M)]
    // [50.33M,83.89M): ctx bf16 (k2-k3) -> t2 (k7-k10)
    // [83.89M,117.44M): t1 / hs32 in-place (k3-k7)
    // [117.44M,...)  : h16, stats
    unsigned short* qkv  = (unsigned short*)(ws + 0);
    float* part1         = (float*)(ws + 0);
    float* fpart         = (float*)(ws + 0);
    unsigned short* hs16 = (unsigned short*)(ws + 33554432);
    unsigned short* ctx  = (unsigned short*)(ws + 50331648);
    float* t2            = (float*)(ws + 50331648);
    float* t1            = (float*)(ws + 83886080);
    unsigned short* h16  = (unsigned short*)(ws + 117440512);
    float* stats         = (float*)(ws + 118489088);

    k_qkv<<<dim3(256, 8), 256, 0, stream>>>(X, Wq, bq, Wk, bk, Wv, bv, qkv);
    k_attn<<<2048, 256, 0, stream>>>(qkv, ctx);
    k_oproj<<<dim3(256, 4), 256, 0, stream>>>(ctx, Wo, bo, X, t1);
    k_ln1<<<4096, 256, 0, stream>>>(t1, g1, b1v, hs16);
    k_ffn1<<<dim3(32, 16), 256, 0, stream>>>(hs16, W1, part1);
    k_ffn1red<<<512, 256, 0, stream>>>(part1, b1, h16);
    k_ffn2<<<512, 256, 0, stream>>>(h16, W2, b2, t1, t2);
    k_ln2stats<<<256, 256, 0, stream>>>(t2, stats);
    k_fgemm<<<KSF, 256, 0, stream>>>(t2, g2, b2v, Wf, fpart);
    k_fout<<<256, 64, 0, stream>>>(fpart, stats, bfv, out);
}

// Round 2
// 844.578 us; speedup vs baseline: 1.2181x; 1.2181x over previous
//
#include <hip/hip_runtime.h>

#define BB   256
#define SS   64
#define DD   512
#define HH   8
#define DKK  64
#define BSZ  16384   // B*S
#define INSZ 32768
#define DFF  2048
#define NOUT 50
#define KSF  256     // final gemm split-K count
#define KCF  128     // 32768 / KSF

typedef float f32x4 __attribute__((ext_vector_type(4)));
typedef __bf16 bf16x8 __attribute__((ext_vector_type(8)));
typedef unsigned short u16x8 __attribute__((ext_vector_type(8)));

__device__ inline unsigned short f2bf(float f) {
    unsigned u = __builtin_bit_cast(unsigned, f);
    u += 0x7FFFu + ((u >> 16) & 1u);   // RNE
    return (unsigned short)(u >> 16);
}
__device__ inline bf16x8 ld_frag(const unsigned short* p) {
    return __builtin_bit_cast(bf16x8, *(const u16x8*)p);
}
#define MFMA(a,b,c) __builtin_amdgcn_mfma_f32_16x16x32_bf16(a,b,c,0,0,0)

// XOR-swizzled LDS tile addressing: row stride 64 ushorts (128B), 16B chunks
// permuted by row&7. Writes of 8B/16B hit the bank floor; b128 frag reads are
// 2-way (free). col must keep (col&7) meaning: xor only touches bits >=3.
__device__ inline int sw(int row, int col) {
    return row * 64 + ((((col >> 3) ^ (row & 7)) << 3) | (col & 7));
}

// Stage a 64k x 64n fp32 W block (row-major [k][ldn]) into Bs as [n][k] bf16,
// XOR-swizzled. 8 strided dword loads per thread (each instr = 256B coalesced
// across the wave), one ds_write_b128 per 8 values. Conflict-free.
__device__ inline void stage_w64(const float* __restrict__ W, int ldn,
                                 unsigned short* Bs, int tid) {
    const int n = tid & 63, wq = tid >> 6;
    #pragma unroll
    for (int p = 0; p < 2; ++p) {
        const int k0 = wq * 8 + p * 32;
        const float* src = W + (size_t)k0 * ldn + n;
        unsigned short tmp[8];
        #pragma unroll
        for (int j = 0; j < 8; ++j) tmp[j] = f2bf(src[(size_t)j * ldn]);
        *(u16x8*)&Bs[sw(n, k0)] = *(const u16x8*)tmp;
    }
}

// Stage a 256-row x 64-col bf16 A block into As, XOR-swizzled. src row stride
// lds_ (elements). 16B loads, 16B writes, conflict-free.
__device__ inline void stage_a256(const unsigned short* __restrict__ src, int lds_,
                                  unsigned short* As, int tid) {
    #pragma unroll
    for (int p = 0; p < 8; ++p) {
        int e = tid + p * 256;
        int r = e >> 3, c8 = (e & 7) * 8;
        u16x8 v = *(const u16x8*)(src + (size_t)r * lds_ + c8);
        *(u16x8*)&As[sw(r, c8)] = v;
    }
}

// ---------------------------------------------------------------- X -> bf16
__global__ __launch_bounds__(256) void k_x16(
    const float* __restrict__ X, unsigned short* __restrict__ x16)
{
    int e = blockIdx.x * 256 + threadIdx.x;   // float4 index, 2M total
    float4 v = ((const float4*)X)[e];
    ushort4 u;
    u.x = f2bf(v.x); u.y = f2bf(v.y); u.z = f2bf(v.z); u.w = f2bf(v.w);
    ((ushort4*)x16)[e] = u;
}

// ---------------------------------------------------------------- QKV fused
// One GEMM: M=16384, N=1536 (3 mats x 8 heads x 64), K=512.
// grid (64 m-tiles of 256, 24 n-tiles of 64). n-tile = (w3, h).
__global__ __launch_bounds__(256) void k_qkv(
    const unsigned short* __restrict__ x16,
    const float* __restrict__ Wq, const float* __restrict__ bq,
    const float* __restrict__ Wk, const float* __restrict__ bk,
    const float* __restrict__ Wv, const float* __restrict__ bv,
    unsigned short* __restrict__ qkv)
{
    const int m0 = blockIdx.x * 256;
    const int nt = blockIdx.y, w3 = nt >> 3, h = nt & 7;
    const int tid = threadIdx.x, wave = tid >> 6, lane = tid & 63;
    const float* Wbase = ((w3 == 0) ? Wq : (w3 == 1) ? Wk : Wv) + (size_t)h * DD * DKK;
    __shared__ __align__(16) unsigned short As[256 * 64];
    __shared__ __align__(16) unsigned short Bs[64 * 64];

    f32x4 acc[4][4] = {};
    for (int k0 = 0; k0 < DD; k0 += 64) {
        stage_a256(x16 + (size_t)m0 * DD + k0, DD, As, tid);
        stage_w64(Wbase + (size_t)k0 * DKK, DKK, Bs, tid);
        __syncthreads();
        #pragma unroll
        for (int ks = 0; ks < 64; ks += 32) {
            bf16x8 bfr[4];
            #pragma unroll
            for (int n2 = 0; n2 < 4; ++n2)
                bfr[n2] = ld_frag(&Bs[sw(n2*16 + (lane & 15), ks + (lane >> 4) * 8)]);
            #pragma unroll
            for (int m2 = 0; m2 < 4; ++m2) {
                bf16x8 a = ld_frag(&As[sw(wave*64 + m2*16 + (lane & 15), ks + (lane >> 4) * 8)]);
                #pragma unroll
                for (int n2 = 0; n2 < 4; ++n2) acc[m2][n2] = MFMA(a, bfr[n2], acc[m2][n2]);
            }
        }
        __syncthreads();
    }
    const float* bias = ((w3 == 0) ? bq : (w3 == 1) ? bk : bv) + h * DKK;
    const float scale = (w3 == 0) ? 0.125f : 1.0f;
    #pragma unroll
    for (int m2 = 0; m2 < 4; ++m2)
        #pragma unroll
        for (int n2 = 0; n2 < 4; ++n2)
            #pragma unroll
            for (int r = 0; r < 4; ++r) {
                int m = m0 + wave*64 + m2*16 + (lane >> 4) * 4 + r;
                int b = m >> 6, s = m & 63;
                int dk = n2*16 + (lane & 15);
                qkv[((size_t)(w3 * BB + b) * HH + h) * 4096 + s * 64 + dk]
                    = f2bf((acc[m2][n2][r] + bias[dk]) * scale);
            }
}

// ---------------------------------------------------------------- attention
__global__ __launch_bounds__(256) void k_attn(
    const unsigned short* __restrict__ qkv, unsigned short* __restrict__ ctx)
{
    const int b = blockIdx.x >> 3, h = blockIdx.x & 7;
    const int tid = threadIdx.x, wave = tid >> 6, lane = tid & 63;
    __shared__ __align__(16) unsigned short Qs[64*64], Ks[64*64], Vt[64*64], Ps[64*64];

    const unsigned short* qp = qkv + ((size_t)(0 * BB + b) * HH + h) * 4096;
    const unsigned short* kp = qkv + ((size_t)(1 * BB + b) * HH + h) * 4096;
    const unsigned short* vp = qkv + ((size_t)(2 * BB + b) * HH + h) * 4096;

    #pragma unroll
    for (int p = 0; p < 2; ++p) {
        int e = tid + p * 256;
        int r = e >> 3, c8 = (e & 7) * 8;
        *(u16x8*)&Qs[sw(r, c8)] = *(const u16x8*)(qp + r * 64 + c8);
        *(u16x8*)&Ks[sw(r, c8)] = *(const u16x8*)(kp + r * 64 + c8);
    }
    {   // V transposed: thread gathers 16 t's for one dv, two b128 writes
        int dv = tid & 63, tb = (tid >> 6) * 16;
        unsigned short tmp[16];
        #pragma unroll
        for (int i = 0; i < 16; ++i) tmp[i] = vp[(tb + i) * 64 + dv];
        *(u16x8*)&Vt[sw(dv, tb)]     = *(const u16x8*)&tmp[0];
        *(u16x8*)&Vt[sw(dv, tb + 8)] = *(const u16x8*)&tmp[8];
    }
    __syncthreads();

    f32x4 sa[4] = {};
    #pragma unroll
    for (int ks = 0; ks < 64; ks += 32) {
        bf16x8 a = ld_frag(&Qs[sw(wave*16 + (lane & 15), ks + (lane >> 4) * 8)]);
        #pragma unroll
        for (int n2 = 0; n2 < 4; ++n2) {
            bf16x8 bb = ld_frag(&Ks[sw(n2*16 + (lane & 15), ks + (lane >> 4) * 8)]);
            sa[n2] = MFMA(a, bb, sa[n2]);
        }
    }
    #pragma unroll
    for (int r = 0; r < 4; ++r) {
        float mx = fmaxf(fmaxf(sa[0][r], sa[1][r]), fmaxf(sa[2][r], sa[3][r]));
        for (int off = 1; off < 16; off <<= 1) mx = fmaxf(mx, __shfl_xor(mx, off, 64));
        float e0 = __expf(sa[0][r] - mx), e1 = __expf(sa[1][r] - mx);
        float e2 = __expf(sa[2][r] - mx), e3 = __expf(sa[3][r] - mx);
        float sm = e0 + e1 + e2 + e3;
        for (int off = 1; off < 16; off <<= 1) sm += __shfl_xor(sm, off, 64);
        float inv = 1.f / sm;
        sa[0][r] = e0 * inv; sa[1][r] = e1 * inv; sa[2][r] = e2 * inv; sa[3][r] = e3 * inv;
    }
    #pragma unroll
    for (int n2 = 0; n2 < 4; ++n2)
        #pragma unroll
        for (int r = 0; r < 4; ++r)
            Ps[sw(wave*16 + (lane >> 4)*4 + r, n2*16 + (lane & 15))] = f2bf(sa[n2][r]);
    __syncthreads();

    f32x4 oa[4] = {};
    #pragma unroll
    for (int ks = 0; ks < 64; ks += 32) {
        bf16x8 a = ld_frag(&Ps[sw(wave*16 + (lane & 15), ks + (lane >> 4) * 8)]);
        #pragma unroll
        for (int n2 = 0; n2 < 4; ++n2) {
            bf16x8 bb = ld_frag(&Vt[sw(n2*16 + (lane & 15), ks + (lane >> 4) * 8)]);
            oa[n2] = MFMA(a, bb, oa[n2]);
        }
    }
    unsigned short* cp = ctx + (size_t)b * SS * DD + h * DKK;
    #pragma unroll
    for (int n2 = 0; n2 < 4; ++n2)
        #pragma unroll
        for (int r = 0; r < 4; ++r) {
            int s = wave*16 + (lane >> 4)*4 + r;
            cp[(size_t)s * DD + n2*16 + (lane & 15)] = f2bf(oa[n2][r]);
        }
}

// ---------------------------------------------------------------- out-proj
// grid (64 m-tiles of 256, 8 n-tiles of 64), K=512. t1 = ctx@Wo + bo + X
__global__ __launch_bounds__(256) void k_oproj(
    const unsigned short* __restrict__ ctx, const float* __restrict__ Wo,
    const float* __restrict__ bo, const float* __restrict__ X,
    float* __restrict__ t1)
{
    const int m0 = blockIdx.x * 256, n0 = blockIdx.y * 64;
    const int tid = threadIdx.x, wave = tid >> 6, lane = tid & 63;
    __shared__ __align__(16) unsigned short As[256 * 64];
    __shared__ __align__(16) unsigned short Bs[64 * 64];
    f32x4 acc[4][4] = {};
    for (int k0 = 0; k0 < DD; k0 += 64) {
        stage_a256(ctx + (size_t)m0 * DD + k0, DD, As, tid);
        stage_w64(Wo + (size_t)k0 * DD + n0, DD, Bs, tid);
        __syncthreads();
        #pragma unroll
        for (int ks = 0; ks < 64; ks += 32) {
            bf16x8 bfr[4];
            #pragma unroll
            for (int n2 = 0; n2 < 4; ++n2)
                bfr[n2] = ld_frag(&Bs[sw(n2*16 + (lane & 15), ks + (lane >> 4) * 8)]);
            #pragma unroll
            for (int m2 = 0; m2 < 4; ++m2) {
                bf16x8 a = ld_frag(&As[sw(wave*64 + m2*16 + (lane & 15), ks + (lane >> 4) * 8)]);
                #pragma unroll
                for (int n2 = 0; n2 < 4; ++n2) acc[m2][n2] = MFMA(a, bfr[n2], acc[m2][n2]);
            }
        }
        __syncthreads();
    }
    #pragma unroll
    for (int m2 = 0; m2 < 4; ++m2)
        #pragma unroll
        for (int n2 = 0; n2 < 4; ++n2)
            #pragma unroll
            for (int r = 0; r < 4; ++r) {
                int m = m0 + wave*64 + m2*16 + (lane >> 4)*4 + r;
                int n = n0 + n2*16 + (lane & 15);
                t1[(size_t)m * DD + n] = acc[m2][n2][r] + bo[n] + X[(size_t)m * DD + n];
            }
}

// ---------------------------------------------------------------- LN1 (in place) + bf16 copy
__global__ __launch_bounds__(256) void k_ln1(
    float* __restrict__ t1, const float* __restrict__ g,
    const float* __restrict__ bv, unsigned short* __restrict__ hs16)
{
    const int tid = threadIdx.x, wave = tid >> 6, lane = tid & 63;
    const int row = blockIdx.x * 4 + wave;
    float* p = t1 + (size_t)row * DD;
    float4 v0 = *(const float4*)(p + lane * 4);
    float4 v1 = *(const float4*)(p + 256 + lane * 4);
    float s = v0.x + v0.y + v0.z + v0.w + v1.x + v1.y + v1.z + v1.w;
    float q = v0.x*v0.x + v0.y*v0.y + v0.z*v0.z + v0.w*v0.w
            + v1.x*v1.x + v1.y*v1.y + v1.z*v1.z + v1.w*v1.w;
    for (int off = 1; off < 64; off <<= 1) { s += __shfl_xor(s, off, 64); q += __shfl_xor(q, off, 64); }
    float mu = s / DD;
    float rs = rsqrtf(q / DD - mu * mu + 1e-5f);
    float4 g0 = *(const float4*)(g + lane * 4), g1 = *(const float4*)(g + 256 + lane * 4);
    float4 b0 = *(const float4*)(bv + lane * 4), b1 = *(const float4*)(bv + 256 + lane * 4);
    float4 o0, o1;
    o0.x = (v0.x - mu) * rs * g0.x + b0.x; o0.y = (v0.y - mu) * rs * g0.y + b0.y;
    o0.z = (v0.z - mu) * rs * g0.z + b0.z; o0.w = (v0.w - mu) * rs * g0.w + b0.w;
    o1.x = (v1.x - mu) * rs * g1.x + b1.x; o1.y = (v1.y - mu) * rs * g1.y + b1.y;
    o1.z = (v1.z - mu) * rs * g1.z + b1.z; o1.w = (v1.w - mu) * rs * g1.w + b1.w;
    *(float4*)(p + lane * 4) = o0;
    *(float4*)(p + 256 + lane * 4) = o1;
    unsigned short* hp = hs16 + (size_t)row * DD;
    ushort4 u;
    u.x = f2bf(o0.x); u.y = f2bf(o0.y); u.z = f2bf(o0.z); u.w = f2bf(o0.w);
    *(ushort4*)(hp + lane * 4) = u;
    u.x = f2bf(o1.x); u.y = f2bf(o1.y); u.z = f2bf(o1.z); u.w = f2bf(o1.w);
    *(ushort4*)(hp + 256 + lane * 4) = u;
}

// ---------------------------------------------------------------- FFN1 split-K
// grid (32 n-tiles of 64, 16 k-splits of 2048). M=256 whole.
__global__ __launch_bounds__(256) void k_ffn1(
    const unsigned short* __restrict__ hs16, const float* __restrict__ W1,
    float* __restrict__ part)
{
    const int n0 = blockIdx.x * 64, kbase = blockIdx.y * 2048;
    const int tid = threadIdx.x, wave = tid >> 6, lane = tid & 63;
    __shared__ __align__(16) unsigned short As[256 * 64];
    __shared__ __align__(16) unsigned short Bs[64 * 64];
    f32x4 acc[4][4] = {};
    for (int kc = 0; kc < 2048; kc += 64) {
        int k0 = kbase + kc;
        stage_a256(hs16 + k0, INSZ, As, tid);
        stage_w64(W1 + (size_t)k0 * DFF + n0, DFF, Bs, tid);
        __syncthreads();
        #pragma unroll
        for (int ks = 0; ks < 64; ks += 32) {
            bf16x8 bfr[4];
            #pragma unroll
            for (int n2 = 0; n2 < 4; ++n2)
                bfr[n2] = ld_frag(&Bs[sw(n2*16 + (lane & 15), ks + (lane >> 4) * 8)]);
            #pragma unroll
            for (int m2 = 0; m2 < 4; ++m2) {
                bf16x8 a = ld_frag(&As[sw(wave*64 + m2*16 + (lane & 15), ks + (lane >> 4) * 8)]);
                #pragma unroll
                for (int n2 = 0; n2 < 4; ++n2) acc[m2][n2] = MFMA(a, bfr[n2], acc[m2][n2]);
            }
        }
        __syncthreads();
    }
    float* pp = part + (size_t)blockIdx.y * 256 * DFF;
    #pragma unroll
    for (int m2 = 0; m2 < 4; ++m2)
        #pragma unroll
        for (int n2 = 0; n2 < 4; ++n2)
            #pragma unroll
            for (int r = 0; r < 4; ++r) {
                int m = wave*64 + m2*16 + (lane >> 4)*4 + r;
                int n = n0 + n2*16 + (lane & 15);
                pp[(size_t)m * DFF + n] = acc[m2][n2][r];
            }
}

__global__ __launch_bounds__(256) void k_ffn1red(
    const float* __restrict__ part, const float* __restrict__ b1,
    unsigned short* __restrict__ h16)
{
    int e = blockIdx.x * 256 + threadIdx.x;   // float4 index
    int m = e >> 9;
    int c = (e & 511) * 4;
    float4 s = {0.f, 0.f, 0.f, 0.f};
    for (int p = 0; p < 16; ++p) {
        float4 v = *(const float4*)(part + ((size_t)p * 256 + m) * DFF + c);
        s.x += v.x; s.y += v.y; s.z += v.z; s.w += v.w;
    }
    float4 bb = *(const float4*)(b1 + c);
    s.x = fmaxf(s.x + bb.x, 0.f); s.y = fmaxf(s.y + bb.y, 0.f);
    s.z = fmaxf(s.z + bb.z, 0.f); s.w = fmaxf(s.w + bb.w, 0.f);
    ushort4 u; u.x = f2bf(s.x); u.y = f2bf(s.y); u.z = f2bf(s.z); u.w = f2bf(s.w);
    *(ushort4*)(h16 + (size_t)m * DFF + c) = u;
}

// ---------------------------------------------------------------- FFN2 + residual
// grid 512 n-tiles of 64, K=2048 full. t2 = h@W2 + b2 + hs32
__global__ __launch_bounds__(256) void k_ffn2(
    const unsigned short* __restrict__ h16, const float* __restrict__ W2,
    const float* __restrict__ b2, const float* __restrict__ hs32,
    float* __restrict__ t2)
{
    const int n0 = blockIdx.x * 64;
    const int tid = threadIdx.x, wave = tid >> 6, lane = tid & 63;
    __shared__ __align__(16) unsigned short As[256 * 64];
    __shared__ __align__(16) unsigned short Bs[64 * 64];
    f32x4 acc[4][4] = {};
    for (int k0 = 0; k0 < DFF; k0 += 64) {
        stage_a256(h16 + k0, DFF, As, tid);
        stage_w64(W2 + (size_t)k0 * INSZ + n0, INSZ, Bs, tid);
        __syncthreads();
        #pragma unroll
        for (int ks = 0; ks < 64; ks += 32) {
            bf16x8 bfr[4];
            #pragma unroll
            for (int n2 = 0; n2 < 4; ++n2)
                bfr[n2] = ld_frag(&Bs[sw(n2*16 + (lane & 15), ks + (lane >> 4) * 8)]);
            #pragma unroll
            for (int m2 = 0; m2 < 4; ++m2) {
                bf16x8 a = ld_frag(&As[sw(wave*64 + m2*16 + (lane & 15), ks + (lane >> 4) * 8)]);
                #pragma unroll
                for (int n2 = 0; n2 < 4; ++n2) acc[m2][n2] = MFMA(a, bfr[n2], acc[m2][n2]);
            }
        }
        __syncthreads();
    }
    #pragma unroll
    for (int m2 = 0; m2 < 4; ++m2)
        #pragma unroll
        for (int n2 = 0; n2 < 4; ++n2)
            #pragma unroll
            for (int r = 0; r < 4; ++r) {
                int m = wave*64 + m2*16 + (lane >> 4)*4 + r;
                int n = n0 + n2*16 + (lane & 15);
                size_t idx = (size_t)m * INSZ + n;
                t2[idx] = acc[m2][n2][r] + b2[n] + hs32[idx];
            }
}

// ---------------------------------------------------------------- LN2 stats
__global__ __launch_bounds__(256) void k_ln2stats(
    const float* __restrict__ t2, float* __restrict__ stats)
{
    const int m = blockIdx.x, tid = threadIdx.x;
    const float* p = t2 + (size_t)m * INSZ;
    float s = 0.f, q = 0.f;
    for (int i = tid; i < INSZ / 4; i += 256) {
        float4 v = *(const float4*)(p + i * 4);
        s += v.x + v.y + v.z + v.w;
        q += v.x*v.x + v.y*v.y + v.z*v.z + v.w*v.w;
    }
    for (int off = 1; off < 64; off <<= 1) { s += __shfl_xor(s, off, 64); q += __shfl_xor(q, off, 64); }
    __shared__ float ss[4], qq[4];
    if ((tid & 63) == 0) { ss[tid >> 6] = s; qq[tid >> 6] = q; }
    __syncthreads();
    if (tid == 0) {
        s = ss[0] + ss[1] + ss[2] + ss[3];
        q = qq[0] + qq[1] + qq[2] + qq[3];
        float mu = s / INSZ;
        stats[m * 2] = mu;
        stats[m * 2 + 1] = rsqrtf(q / INSZ - mu * mu + 1e-5f);
    }
}

// ---------------------------------------------------------------- final GEMM (LN folded)
// A rows: 0..255 = t2*g ; 256 = g ; 257 = b ; 258..271 = 0. Split-K over 256 blocks.
__global__ __launch_bounds__(256) void k_fgemm(
    const float* __restrict__ t2, const float* __restrict__ g,
    const float* __restrict__ bv, const float* __restrict__ Wf,
    float* __restrict__ fpart)
{
    const int sp = blockIdx.x, kbase = sp * KCF;
    const int tid = threadIdx.x, wave = tid >> 6, lane = tid & 63;
    __shared__ __align__(16) unsigned short As[272][72];
    __shared__ __align__(16) unsigned short Bs[64 * 64];
    f32x4 acc[5][4] = {};
    for (int kc = 0; kc < KCF; kc += 64) {
        int k0 = kbase + kc;
        for (int p = 0; p < 68; ++p) {
            int e = tid + p * 256;
            int r = e >> 6, c = e & 63;
            int k = k0 + c;
            float val;
            if (r < 256)       val = t2[(size_t)r * INSZ + k] * g[k];
            else if (r == 256) val = g[k];
            else if (r == 257) val = bv[k];
            else               val = 0.f;
            As[r][c] = f2bf(val);
        }
        {   // Wf block: strided loads, b128 writes (n>=NOUT zero-padded)
            int n = tid & 63, wq = tid >> 6;
            #pragma unroll
            for (int p = 0; p < 2; ++p) {
                int kk = wq * 8 + p * 32;
                unsigned short tmp[8];
                #pragma unroll
                for (int j = 0; j < 8; ++j)
                    tmp[j] = (n < NOUT) ? f2bf(Wf[(size_t)(k0 + kk + j) * NOUT + n]) : (unsigned short)0;
                *(u16x8*)&Bs[sw(n, kk)] = *(const u16x8*)tmp;
            }
        }
        __syncthreads();
        #pragma unroll
        for (int ks = 0; ks < 64; ks += 32) {
            bf16x8 bfr[4];
            #pragma unroll
            for (int n2 = 0; n2 < 4; ++n2)
                bfr[n2] = ld_frag(&Bs[sw(n2*16 + (lane & 15), ks + (lane >> 4) * 8)]);
            int i = 0;
            for (int mt = wave; mt < 17; mt += 4, ++i) {
                bf16x8 a = ld_frag(&As[mt*16 + (lane & 15)][ks + (lane >> 4) * 8]);
                #pragma unroll
                for (int n2 = 0; n2 < 4; ++n2) acc[i][n2] = MFMA(a, bfr[n2], acc[i][n2]);
            }
        }
        __syncthreads();
    }
    int i = 0;
    for (int mt = wave; mt < 17; mt += 4, ++i)
        #pragma unroll
        for (int n2 = 0; n2 < 4; ++n2)
            #pragma unroll
            for (int r = 0; r < 4; ++r) {
                int m = mt*16 + (lane >> 4)*4 + r;
                int n = n2*16 + (lane & 15);
                fpart[((size_t)m * KSF + sp) * 64 + n] = acc[i][n2][r];
            }
}

__global__ __launch_bounds__(256) void k_fout(
    const float* __restrict__ fpart, const float* __restrict__ stats,
    const float* __restrict__ bf_, float* __restrict__ out)
{
    const int m = blockIdx.x, tid = threadIdx.x;
    const int n = tid & 63, sq = tid >> 6;
    float s = 0.f, sg = 0.f, sb = 0.f;
    for (int sp = sq * 64; sp < sq * 64 + 64; ++sp) {
        s  += fpart[((size_t)m   * KSF + sp) * 64 + n];
        sg += fpart[((size_t)256 * KSF + sp) * 64 + n];
        sb += fpart[((size_t)257 * KSF + sp) * 64 + n];
    }
    __shared__ float red[3][4][64];
    red[0][sq][n] = s; red[1][sq][n] = sg; red[2][sq][n] = sb;
    __syncthreads();
    if (tid < NOUT) {
        float S  = red[0][0][tid] + red[0][1][tid] + red[0][2][tid] + red[0][3][tid];
        float SG = red[1][0][tid] + red[1][1][tid] + red[1][2][tid] + red[1][3][tid];
        float SB = red[2][0][tid] + red[2][1][tid] + red[2][2][tid] + red[2][3][tid];
        float mu = stats[m * 2], rv = stats[m * 2 + 1];
        out[m * NOUT + tid] = rv * (S - mu * SG) + SB + bf_[tid];
    }
}

// ---------------------------------------------------------------- launch
extern "C" void kernel_launch(void* const* d_in, const int* in_sizes, int n_in,
                              void* d_out, int out_size, void* d_ws, size_t ws_size,
                              hipStream_t stream) {
    const float* X   = (const float*)d_in[0];
    const float* Wq  = (const float*)d_in[1];
    const float* bq  = (const float*)d_in[2];
    const float* Wk  = (const float*)d_in[3];
    const float* bk  = (const float*)d_in[4];
    const float* Wv  = (const float*)d_in[5];
    const float* bv  = (const float*)d_in[6];
    const float* Wo  = (const float*)d_in[7];
    const float* bo  = (const float*)d_in[8];
    const float* g1  = (const float*)d_in[9];
    const float* b1v = (const float*)d_in[10];
    const float* W1  = (const float*)d_in[11];
    const float* b1  = (const float*)d_in[12];
    const float* W2  = (const float*)d_in[13];
    const float* b2  = (const float*)d_in[14];
    const float* g2  = (const float*)d_in[15];
    const float* b2v = (const float*)d_in[16];
    const float* Wf  = (const float*)d_in[17];
    const float* bfv = (const float*)d_in[18];
    float* out = (float*)d_out;
    char* ws = (char*)d_ws;

    // workspace overlay (liveness-checked):
    //  x16   @        0 .. 16.78M   (k_x16 -> k_qkv)
    //  qkv   @ 16.78M .. 67.11M   (k_qkv -> k_attn)
    //  ctx   @ 67.11M .. 83.89M   (k_attn -> k_oproj)
    //  t1    @ 83.89M ..117.44M   (k_oproj -> k_ffn2, LN1 in place)
    //  hs16  @        0 .. 16.78M   (k_ln1 -> k_ffn1; x16 dead)
    //  part1 @ 16.78M .. 50.33M   (k_ffn1 -> k_ffn1red; qkv dead)
    //  h16   @ 50.33M .. 51.38M   (k_ffn1red -> k_ffn2)
    //  t2    @        0 .. 33.55M   (k_ffn2 -> k_fgemm; hs16/part1 dead)
    //  fpart @ 33.55M .. 51.38M   (k_fgemm -> k_fout; part1/h16 dead)
    //  stats @ 51.38M             (k_ln2stats -> k_fout)
    unsigned short* x16  = (unsigned short*)(ws + 0);
    unsigned short* qkv  = (unsigned short*)(ws + 16777216);
    unsigned short* ctx  = (unsigned short*)(ws + 67108864);
    float* t1            = (float*)(ws + 83886080);
    unsigned short* hs16 = (unsigned short*)(ws + 0);
    float* part1         = (float*)(ws + 16777216);
    unsigned short* h16  = (unsigned short*)(ws + 50331648);
    float* t2            = (float*)(ws + 0);
    float* fpart         = (float*)(ws + 33554432);
    float* stats         = (float*)(ws + 51380224);

    k_x16<<<8192, 256, 0, stream>>>(X, x16);
    k_qkv<<<dim3(64, 24), 256, 0, stream>>>(x16, Wq, bq, Wk, bk, Wv, bv, qkv);
    k_attn<<<2048, 256, 0, stream>>>(qkv, ctx);
    k_oproj<<<dim3(64, 8), 256, 0, stream>>>(ctx, Wo, bo, X, t1);
    k_ln1<<<4096, 256, 0, stream>>>(t1, g1, b1v, hs16);
    k_ffn1<<<dim3(32, 16), 256, 0, stream>>>(hs16, W1, part1);
    k_ffn1red<<<512, 256, 0, stream>>>(part1, b1, h16);
    k_ffn2<<<512, 256, 0, stream>>>(h16, W2, b2, t1, t2);
    k_ln2stats<<<256, 256, 0, stream>>>(t2, stats);
    k_fgemm<<<KSF, 256, 0, stream>>>(t2, g2, b2v, Wf, fpart);
    k_fout<<<256, 256, 0, stream>>>(fpart, stats, bfv, out);
}